// Round 8
// baseline (139.679 us; speedup 1.0000x reference)
//
#include <hip/hip_runtime.h>

// SGAN_PoolingNet: pooled[i] = max_j relu( relu([hidden[j], (ends[j]-ends[i])@We+be] @ W1 + b1) @ W2 + b2 )
// Collapse: y_lin[i,j,:] = A[j,:] - U[i,:]
//   A[j,k] = hidden[j]@W1[0:64,k] + ends[j]@M2[:,k] + b1[k] + be@W1[64:80,k]   (f32 math, stored bf16)
//   U[i,k] = ends[i]@M2[:,k]  (precomputed f32 in prep_all — it already has m20/m21)
// pool_main: block = (agent i, j-quarter h); Z = relu(A - U[i]) @ W2 via mfma_f32_16x16x32_bf16
// (mapping verified R3/R6/R7), partial row-max -> part[]. finish: max over h, +b2, relu.
// R8 theory: R7 halved VALU (52->27.5%) yet dur pinned ~49us, all pipes <30% -> stall-bound at
// 2-3 waves/SIMD (R7 combined regs ~244/wave). Fix concurrency: 4096 blocks (16x residency) so
// CUs always have blocks in different phases to overlap the load->pack->MFMA serial chains.

#define N_AG 1024

typedef __attribute__((ext_vector_type(8))) short short8;        // 8 bf16 = 4 VGPR (MFMA A/B frag)
typedef __attribute__((ext_vector_type(4))) float floatx4;       // MFMA C/D frag
typedef __attribute__((ext_vector_type(4))) unsigned int uintx4; // 4 packed bf16 pairs

__device__ __forceinline__ unsigned short f2bf(float f) {
  unsigned u = __builtin_bit_cast(unsigned, f);
  u += 0x7FFFu + ((u >> 16) & 1u);   // RNE (prep only)
  return (unsigned short)(u >> 16);
}

// pack two f32 -> bf16 pair by truncation (RTZ): one v_perm_b32 (verified R7, absmax 0.03125)
__device__ __forceinline__ unsigned pack2bf_rtz(float y0, float y1) {
  return __builtin_amdgcn_perm(__builtin_bit_cast(unsigned, y1),
                               __builtin_bit_cast(unsigned, y0), 0x07060302u);
}

// ---- prep (fused): block j computes A[j] and U[j]; blocks 0..31 write W2T ----
__global__ __launch_bounds__(128) void prep_all(
    const float* __restrict__ hidden,  // (1,1024,64)
    const float* __restrict__ track,   // (1024,8,2)
    const float* __restrict__ We,      // (2,16)
    const float* __restrict__ be,      // (16)
    const float* __restrict__ W1,      // (80,128)
    const float* __restrict__ b1,      // (128)
    const float* __restrict__ W2,      // (128,64)
    unsigned short* __restrict__ Abf,  // (1024,128) bf16
    float* __restrict__ Uf,            // (1024,128) f32
    unsigned short* __restrict__ W2T)  // (64,128) bf16, transposed
{
  int j = blockIdx.x;
  int k = threadIdx.x;   // 0..127
  __shared__ float hj[64];
  if (k < 64) hj[k] = hidden[j * 64 + k];
  __syncthreads();
  float e0 = track[j * 16 + 14];
  float e1 = track[j * 16 + 15];
  float m20 = 0.f, m21 = 0.f, cb = b1[k];
#pragma unroll
  for (int t = 0; t < 16; ++t) {
    float w1v = W1[(64 + t) * 128 + k];
    m20 += We[t] * w1v;
    m21 += We[16 + t] * w1v;
    cb  += be[t] * w1v;
  }
  float uval = e0 * m20 + e1 * m21;       // U[j][k] — same expression pool_main used (bit-identical)
  Uf[j * 128 + k] = uval;
  float acc = uval + cb;
#pragma unroll 16
  for (int t = 0; t < 64; ++t) acc += hj[t] * W1[t * 128 + k];
  Abf[j * 128 + k] = f2bf(acc);

  if (j < 32) {           // W2T[n][c] = bf16(W2[c][n]); 32 blocks x 256 entries
#pragma unroll
    for (int q = 0; q < 2; ++q) {
      int idx = j * 256 + q * 128 + k;
      int n = idx >> 7, c = idx & 127;
      W2T[n * 128 + c] = f2bf(W2[c * 64 + n]);
    }
  }
}

// ---- main: block = (agent i = bid>>2, j-quarter h = bid&3); 4 waves x 4 iters ----
__global__ __launch_bounds__(256) void pool_main(
    const unsigned short* __restrict__ Abf,   // (1024,128) bf16
    const float* __restrict__ Uf,             // (1024,128) f32
    const unsigned short* __restrict__ W2T,   // (64,128) bf16
    float* __restrict__ part)                 // (4096,64) f32 partial maxima (pre-b2)
{
  const int i    = blockIdx.x >> 2;
  const int h    = blockIdx.x & 3;
  const int lane = threadIdx.x & 63;
  const int wave = threadIdx.x >> 6;
  const int m    = lane & 15;   // A row within tile / B-and-D column
  const int quad = lane >> 4;   // k-subrange selector

  // U[i] for this lane's 32 k's: 8 coalesced dwordx4 loads (was 64 scalar M2 loads)
  float u[4][8];
#pragma unroll
  for (int kk = 0; kk < 4; ++kk) {
    floatx4 ua = *(const floatx4*)(Uf + i * 128 + kk * 32 + quad * 8);
    floatx4 ub = *(const floatx4*)(Uf + i * 128 + kk * 32 + quad * 8 + 4);
#pragma unroll
    for (int jj = 0; jj < 4; ++jj) { u[kk][jj] = ua[jj]; u[kk][4 + jj] = ub[jj]; }
  }

  // B fragments resident in registers
  short8 bfrag[4][4];
#pragma unroll
  for (int t = 0; t < 4; ++t)
#pragma unroll
    for (int kk = 0; kk < 4; ++kk)
      bfrag[t][kk] = *(const short8*)(W2T + (t * 16 + m) * 128 + kk * 32 + quad * 8);

  floatx4 mx[4];
#pragma unroll
  for (int t = 0; t < 4; ++t) mx[t] = (floatx4){-3e38f, -3e38f, -3e38f, -3e38f};

  // this block covers jt in [16h, 16h+16); this wave: jt = 16h + wave + 4s, s=0..3
  const unsigned short* Aptr = Abf + ((16 * h + wave) * 16 + m) * 128 + quad * 8;
#pragma unroll 2
  for (int s = 0; s < 4; ++s, Aptr += 4 * 16 * 128) {
    uintx4 au[4];
#pragma unroll
    for (int kk = 0; kk < 4; ++kk) {
      uintx4 raw = *(const uintx4*)(Aptr + kk * 32);
#pragma unroll
      for (int p = 0; p < 4; ++p) {
        unsigned w = raw[p];
        float lo = __builtin_bit_cast(float, w << 16);          // element 2p   (low half)
        float hi = __builtin_bit_cast(float, w & 0xFFFF0000u);  // element 2p+1 (high half)
        float y0 = fmaxf(lo - u[kk][2 * p], 0.f);
        float y1 = fmaxf(hi - u[kk][2 * p + 1], 0.f);
        au[kk][p] = pack2bf_rtz(y0, y1);
      }
    }
#pragma unroll
    for (int t = 0; t < 4; ++t) {
      floatx4 acc = (floatx4){0.f, 0.f, 0.f, 0.f};
#pragma unroll
      for (int kk = 0; kk < 4; ++kk)
        acc = __builtin_amdgcn_mfma_f32_16x16x32_bf16(
            __builtin_bit_cast(short8, au[kk]), bfrag[t][kk], acc, 0, 0, 0);
#pragma unroll
      for (int r = 0; r < 4; ++r) mx[t][r] = fmaxf(mx[t][r], acc[r]);
    }
  }

  // D layout: row = quad*4 + r (j-dim), col = m. In-lane then cross-quad; cross-wave via LDS.
  float lm[4];
#pragma unroll
  for (int t = 0; t < 4; ++t) {
    lm[t] = fmaxf(fmaxf(mx[t][0], mx[t][1]), fmaxf(mx[t][2], mx[t][3]));
    lm[t] = fmaxf(lm[t], __shfl_xor(lm[t], 16, 64));
    lm[t] = fmaxf(lm[t], __shfl_xor(lm[t], 32, 64));
  }
  __shared__ float red[4][64];
  if (quad == 0) {
#pragma unroll
    for (int t = 0; t < 4; ++t) red[wave][t * 16 + m] = lm[t];
  }
  __syncthreads();
  if (threadIdx.x < 64) {
    int n = threadIdx.x;
    part[blockIdx.x * 64 + n] =
        fmaxf(fmaxf(red[0][n], red[1][n]), fmaxf(red[2][n], red[3][n]));
  }
}

// ---- finish: out[i,n] = relu(max_h part[(4i+h),n] + b2[n]) ----
__global__ __launch_bounds__(256) void finish(
    const float* __restrict__ part,   // (4096,64)
    const float* __restrict__ b2,     // (64)
    float* __restrict__ out)          // (1024,64)
{
  int idx = blockIdx.x * 256 + threadIdx.x;  // 0..65535
  int i = idx >> 6, n = idx & 63;
  float v = fmaxf(fmaxf(part[(4 * i) * 64 + n], part[(4 * i + 1) * 64 + n]),
                  fmaxf(part[(4 * i + 2) * 64 + n], part[(4 * i + 3) * 64 + n]));
  v += b2[n];
  out[idx] = v > 0.f ? v : 0.f;
}

extern "C" void kernel_launch(void* const* d_in, const int* in_sizes, int n_in,
                              void* d_out, int out_size, void* d_ws, size_t ws_size,
                              hipStream_t stream) {
  const float* hidden = (const float*)d_in[0]; // (1,1024,64)
  const float* track  = (const float*)d_in[1]; // (1024,8,2)
  const float* We     = (const float*)d_in[2]; // (2,16)
  const float* be     = (const float*)d_in[3]; // (16)
  const float* W1     = (const float*)d_in[4]; // (80,128)
  const float* b1     = (const float*)d_in[5]; // (128)
  const float* W2     = (const float*)d_in[6]; // (128,64)
  const float* b2     = (const float*)d_in[7]; // (64)
  float* out = (float*)d_out;

  char* ws = (char*)d_ws;
  unsigned short* Abf = (unsigned short*)ws;              // 256 KiB   @ 0
  unsigned short* W2T = (unsigned short*)(ws + 262144);   // 16 KiB    @ 256K
  float*          Uf  = (float*)(ws + 280576);            // 512 KiB   @ ~274K (16B aligned)
  float*          prt = (float*)(ws + 804864);            // 1 MiB     @ ~786K (16B aligned)

  prep_all<<<N_AG, 128, 0, stream>>>(hidden, track, We, be, W1, b1, W2, Abf, Uf, W2T);
  pool_main<<<N_AG * 4, 256, 0, stream>>>(Abf, Uf, W2T, prt);
  finish<<<256, 256, 0, stream>>>(prt, b2, out);
}